// Round 1
// baseline (363.705 us; speedup 1.0000x reference)
//
#include <hip/hip_runtime.h>
#include <hip/hip_bf16.h>

typedef short short8 __attribute__((ext_vector_type(8)));
typedef float f32x4 __attribute__((ext_vector_type(4)));

#define XSTRIDE 264  // bf16 elements per LDS row: 256 + 8 pad (528 B -> 4-bank shift/row, 2-way free)

static __device__ inline short f2bf(float f) {
    unsigned u = __float_as_uint(f);
    unsigned r = (u + 0x7fffu + ((u >> 16) & 1u)) >> 16;
    return (short)r;
}
static __device__ inline float bf2f(short s) {
    return __uint_as_float(((unsigned)(unsigned short)s) << 16);
}

// Wu[d][j] = W1[d][j] - W1[256+d][j]   (the tgt-coefficient matrix W1a - W1c)
__global__ void make_wu(const float* __restrict__ W1, float* __restrict__ Wu) {
    int idx = blockIdx.x * 256 + threadIdx.x;           // 128*256 = 32768
    Wu[idx] = W1[idx] - W1[idx + 256 * 256];
}

// Repack Wcat (256x256) into MFMA B-fragment order, bf16.
// Wcat[k][n]: k<128 -> W1b[k][n]+W1c[k][n];  k>=128 -> W1d[k-128][n]
// Wfrag[((t*8+s)*64+l)*8+j] = Wcat[s*32 + (l>>4)*8 + j][t*16 + (l&15)]
__global__ void repack_w(const float* __restrict__ W1, short* __restrict__ Wfrag) {
    int idx = blockIdx.x * 256 + threadIdx.x;           // 65536 total
    int j = idx & 7;
    int l = (idx >> 3) & 63;
    int s = (idx >> 9) & 7;
    int t = idx >> 12;
    int k = s * 32 + ((l >> 4) << 3) + j;
    int n = t * 16 + (l & 15);
    float v;
    if (k < 128) v = W1[(128 + k) * 256 + n] + W1[(256 + k) * 256 + n];
    else         v = W1[(384 + (k - 128)) * 256 + n];
    Wfrag[idx] = f2bf(v);
}

// U[b][j] = b1[j] + sum_d target[b][d] * Wu[d][j]   (f32, exact path for the bias-like term)
__global__ void compute_u(const float* __restrict__ target, const float* __restrict__ Wu,
                          const float* __restrict__ b1, float* __restrict__ U) {
    int b = blockIdx.x;
    int j = threadIdx.x;
    __shared__ float tl[128];
    if (j < 128) tl[j] = target[b * 128 + j];
    __syncthreads();
    float acc = b1[j];
#pragma unroll 8
    for (int d = 0; d < 128; ++d) acc += tl[d] * Wu[d * 256 + j];
    U[b * 256 + j] = acc;
}

// Main fused kernel: one block per batch element b; 4 waves.
// h_pre[l][j] = U[b][j] + X[l] @ Wcat[:,j],  X[l] = [item[l], item[l]*tgt]  (bf16 MFMA, K=256)
// score[l] = relu(h_pre[l]) @ W2 + b2;  out[b][d] = sum_l mask(l) * score[l] * item[l][d]
__launch_bounds__(256, 2)
__global__ void din_main(const float* __restrict__ target, const float* __restrict__ item_seq,
                         const int* __restrict__ seq_len, const float* __restrict__ W2,
                         const float* __restrict__ b2p, const short* __restrict__ Wfrag,
                         const float* __restrict__ U, float* __restrict__ out) {
    const int b = blockIdx.x;
    const int tid = threadIdx.x;
    const int lane = tid & 63;
    const int wave = tid >> 6;
    const int col = lane & 15;   // MFMA C-layout col, and B-frag n
    const int q = lane >> 4;     // quad: C rows q*4..q*4+3, A/B k-offset q*8

    __shared__ __attribute__((aligned(16))) short Xl[16 * XSTRIDE];
    __shared__ float u_s[256];
    __shared__ float w2_s[256];
    __shared__ float scoreP[4][16];
    __shared__ float out_s[128];

    u_s[tid] = U[b * 256 + tid];
    w2_s[tid] = W2[tid];
    const float b2 = b2p[0];
    const int slen = seq_len[b];

    // Staging assignment (fixed per thread): row r, cols c..c+7
    const int r = tid >> 4;
    const int c = (tid & 15) << 3;
    float tgt8[8];
#pragma unroll
    for (int i = 0; i < 8; i++) tgt8[i] = target[b * 128 + c + i];

    // B fragments for this wave's 4 N-tiles, all 8 K-steps: resident in registers.
    short8 bfrag[4][8];
    {
        const short* base = Wfrag + ((size_t)(wave * 32) * 64 + lane) * 8;
#pragma unroll
        for (int i = 0; i < 4; i++)
#pragma unroll
            for (int s = 0; s < 8; s++)
                bfrag[i][s] = *(const short8*)(base + (size_t)((i * 8 + s) * 64) * 8);
    }

    float out_val = 0.f;
    f32x4 acc[4];

    for (int mt = 0; mt < 13; ++mt) {
        const int l0 = mt * 16;
        __syncthreads();  // previous tile's readers done before restage

        // Stage X tile: item (k 0..127) and item*tgt (k 128..255), bf16
        {
            int lr = l0 + r;
            if (lr > 199) lr = 199;  // clamped rows are masked out below
            const float4* src = (const float4*)(item_seq + ((b * 200 + lr) * 128 + c));
            float4 v0 = src[0], v1 = src[1];
            float v[8] = {v0.x, v0.y, v0.z, v0.w, v1.x, v1.y, v1.z, v1.w};
            short8 p0, p1;
#pragma unroll
            for (int i = 0; i < 8; i++) {
                p0[i] = f2bf(v[i]);
                p1[i] = f2bf(v[i] * tgt8[i]);
            }
            short* xr = Xl + r * XSTRIDE;
            *(short8*)(xr + c) = p0;
            *(short8*)(xr + 128 + c) = p1;
        }
        __syncthreads();

#pragma unroll
        for (int i = 0; i < 4; i++) acc[i] = (f32x4){0.f, 0.f, 0.f, 0.f};

        const short* arow = Xl + col * XSTRIDE + q * 8;
#pragma unroll
        for (int s = 0; s < 8; s++) {
            short8 afrag = *(const short8*)(arow + s * 32);
#pragma unroll
            for (int i = 0; i < 4; i++)
                acc[i] = __builtin_amdgcn_mfma_f32_16x16x32_bf16(afrag, bfrag[i][s], acc[i], 0, 0, 0);
        }

        // Epilogue: score[l] partials. Lane holds (row=q*4+rg, col) of each 16x16 tile.
        float sv[4] = {0.f, 0.f, 0.f, 0.f};
#pragma unroll
        for (int i = 0; i < 4; i++) {
            int j = (wave * 4 + i) * 16 + col;
            float uj = u_s[j], wj = w2_s[j];
#pragma unroll
            for (int rg = 0; rg < 4; rg++) {
                float h = acc[i][rg] + uj;
                h = h > 0.f ? h : 0.f;
                sv[rg] += h * wj;
            }
        }
        // reduce over the 16 columns (xor masks 1,2,4,8 stay inside each 16-lane group)
#pragma unroll
        for (int off = 1; off < 16; off <<= 1) {
#pragma unroll
            for (int rg = 0; rg < 4; rg++) sv[rg] += __shfl_xor(sv[rg], off, 64);
        }
        if (col == 0) {
#pragma unroll
            for (int rg = 0; rg < 4; rg++) scoreP[wave][q * 4 + rg] = sv[rg];
        }
        __syncthreads();

        // out[b][d] += sum_m score[m] * item[l0+m][d]; split m-range across thread halves
        {
            int d = tid & 127;
            int mbase = (tid >> 7) * 8;
#pragma unroll
            for (int mm = 0; mm < 8; mm++) {
                int m = mbase + mm;
                int l = l0 + m;
                float s = scoreP[0][m] + scoreP[1][m] + scoreP[2][m] + scoreP[3][m] + b2;
                s = (l < slen) ? s : 0.f;
                out_val += s * bf2f(Xl[m * XSTRIDE + d]);
            }
        }
    }

    __syncthreads();
    if (tid >= 128) out_s[tid - 128] = out_val;
    __syncthreads();
    if (tid < 128) out[b * 128 + tid] = out_val + out_s[tid];
}

extern "C" void kernel_launch(void* const* d_in, const int* in_sizes, int n_in,
                              void* d_out, int out_size, void* d_ws, size_t ws_size,
                              hipStream_t stream) {
    const float* target   = (const float*)d_in[0];
    const float* item_seq = (const float*)d_in[1];
    const int*   seq_len  = (const int*)d_in[2];
    const float* W1       = (const float*)d_in[3];
    const float* b1       = (const float*)d_in[4];
    const float* W2       = (const float*)d_in[5];
    const float* b2       = (const float*)d_in[6];
    float* out = (float*)d_out;

    char* ws = (char*)d_ws;
    float* Wu    = (float*)ws;                  // 128*256*4  = 131072 B
    short* Wfrag = (short*)(ws + 131072);       // 65536*2    = 131072 B
    float* U     = (float*)(ws + 262144);       // 2048*256*4 = 2097152 B

    make_wu<<<128, 256, 0, stream>>>(W1, Wu);
    repack_w<<<256, 256, 0, stream>>>(W1, Wfrag);
    compute_u<<<2048, 256, 0, stream>>>(target, Wu, b1, U);
    din_main<<<2048, 256, 0, stream>>>(target, item_seq, seq_len, W2, b2, Wfrag, U, out);
}

// Round 2
// 334.813 us; speedup vs baseline: 1.0863x; 1.0863x over previous
//
#include <hip/hip_runtime.h>
#include <hip/hip_bf16.h>

typedef short short8 __attribute__((ext_vector_type(8)));
typedef float f32x4 __attribute__((ext_vector_type(4)));

#define XSTRIDE 264  // bf16 elements per LDS row: 256 + 8 pad

static __device__ inline short f2bf(float f) {
    unsigned u = __float_as_uint(f);
    unsigned r = (u + 0x7fffu + ((u >> 16) & 1u)) >> 16;
    return (short)r;
}
static __device__ inline float bf2f(short s) {
    return __uint_as_float(((unsigned)(unsigned short)s) << 16);
}

// Wu[d][j] = W1[d][j] - W1[256+d][j]   (tgt-coefficient matrix W1a - W1c)
__global__ void make_wu(const float* __restrict__ W1, float* __restrict__ Wu) {
    int idx = blockIdx.x * 256 + threadIdx.x;           // 128*256 = 32768
    Wu[idx] = W1[idx] - W1[idx + 256 * 256];
}

// Repack Wcat (256x256) into MFMA B-fragment order, bf16.
// Wcat[k][n]: k<128 -> W1b[k][n]+W1c[k][n];  k>=128 -> W1d[k-128][n]
// Wfrag[((t*8+s)*64+l)*8+j] = Wcat[s*32 + (l>>4)*8 + j][t*16 + (l&15)]
__global__ void repack_w(const float* __restrict__ W1, short* __restrict__ Wfrag) {
    int idx = blockIdx.x * 256 + threadIdx.x;           // 65536 total
    int j = idx & 7;
    int l = (idx >> 3) & 63;
    int s = (idx >> 9) & 7;
    int t = idx >> 12;
    int k = s * 32 + ((l >> 4) << 3) + j;
    int n = t * 16 + (l & 15);
    float v;
    if (k < 128) v = W1[(128 + k) * 256 + n] + W1[(256 + k) * 256 + n];
    else         v = W1[(384 + (k - 128)) * 256 + n];
    Wfrag[idx] = f2bf(v);
}

// Main fused kernel: one block per batch element b; 4 waves.
// U[j]      = b1[j] + target[b] @ Wu[:,j]                       (f32, fused)
// h_pre[l][j] = U[j] + X[l] @ Wcat[:,j], X[l]=[item[l], item[l]*tgt] (bf16 MFMA)
// score[l] = relu(h_pre[l]) @ W2 + b2;  out[b][d] = sum_{l<slen} score[l]*item[l][d]
// Early exit: tiles beyond ceil(slen/16) contribute nothing (mask) -> skip.
__launch_bounds__(256, 2)
__global__ void din_main(const float* __restrict__ target, const float* __restrict__ item_seq,
                         const int* __restrict__ seq_len, const float* __restrict__ W2,
                         const float* __restrict__ b2p, const short* __restrict__ Wfrag,
                         const float* __restrict__ Wu, const float* __restrict__ b1,
                         float* __restrict__ out) {
    const int b = blockIdx.x;
    const int tid = threadIdx.x;
    const int lane = tid & 63;
    const int wave = tid >> 6;
    const int col = lane & 15;   // MFMA C-layout col / B-frag n
    const int q = lane >> 4;     // quad: C rows q*4..q*4+3, A/B k-offset q*8

    __shared__ __attribute__((aligned(16))) short Xl[16 * XSTRIDE];
    __shared__ __attribute__((aligned(16))) float tshared[128];
    __shared__ float u_s[256];
    __shared__ float w2_s[256];
    __shared__ float scoreP[4][16];
    __shared__ float out_s[128];

    const int slen = seq_len[b];
    const int ntiles = (slen + 15) >> 4;
    const float b2 = b2p[0];

    // Staging assignment (fixed per thread): row r, cols c..c+7
    const int r = tid >> 4;
    const int c = (tid & 15) << 3;

    // ---- Prefetch tile 0 into registers (overlaps everything below) ----
    float4 v0, v1;
    if (ntiles > 0) {
        int lr = r;                     // tile 0: rows 0..15, all < 200
        const float4* src = (const float4*)(item_seq + (((size_t)b * 200 + lr) * 128 + c));
        v0 = src[0]; v1 = src[1];
    }

    if (tid < 128) tshared[tid] = target[b * 128 + tid];
    w2_s[tid] = W2[tid];
    __syncthreads();

    // ---- Fused U: u_s[j] = b1[j] + sum_d tshared[d]*Wu[d*256+j] ----
    {
        float uacc = b1[tid];
#pragma unroll 8
        for (int d = 0; d < 128; ++d) uacc += tshared[d] * Wu[d * 256 + tid];
        u_s[tid] = uacc;
    }

    float tgt8[8];
    {
        const float4* t4 = (const float4*)(tshared + c);
        float4 ta = t4[0], tb = t4[1];
        tgt8[0] = ta.x; tgt8[1] = ta.y; tgt8[2] = ta.z; tgt8[3] = ta.w;
        tgt8[4] = tb.x; tgt8[5] = tb.y; tgt8[6] = tb.z; tgt8[7] = tb.w;
    }

    // ---- B fragments: this wave's 4 N-tiles × 8 K-steps, resident in registers ----
    short8 bfrag[4][8];
    {
        const short* base = Wfrag + ((size_t)(wave * 32) * 64 + lane) * 8;
#pragma unroll
        for (int i = 0; i < 4; i++)
#pragma unroll
            for (int s = 0; s < 8; s++)
                bfrag[i][s] = *(const short8*)(base + (size_t)((i * 8 + s) * 64) * 8);
    }

    float out_val = 0.f;
    f32x4 acc[4];

    for (int mt = 0; mt < ntiles; ++mt) {
        const int l0 = mt * 16;
        __syncthreads();  // previous tile's Xl readers done before restage

        // Pack prefetched registers -> Xl (item rows k 0..127, item*tgt k 128..255)
        {
            float v[8] = {v0.x, v0.y, v0.z, v0.w, v1.x, v1.y, v1.z, v1.w};
            short8 p0, p1;
#pragma unroll
            for (int i = 0; i < 8; i++) {
                p0[i] = f2bf(v[i]);
                p1[i] = f2bf(v[i] * tgt8[i]);
            }
            short* xr = Xl + r * XSTRIDE;
            *(short8*)(xr + c) = p0;
            *(short8*)(xr + 128 + c) = p1;
        }
        __syncthreads();

        // ---- Prefetch next tile (overlaps MFMA + epilogue) ----
        if (mt + 1 < ntiles) {
            int lr = l0 + 16 + r;
            if (lr > 199) lr = 199;     // clamped rows masked out later
            const float4* src = (const float4*)(item_seq + (((size_t)b * 200 + lr) * 128 + c));
            v0 = src[0]; v1 = src[1];
        }

#pragma unroll
        for (int i = 0; i < 4; i++) acc[i] = (f32x4){0.f, 0.f, 0.f, 0.f};

        const short* arow = Xl + col * XSTRIDE + q * 8;
#pragma unroll
        for (int s = 0; s < 8; s++) {
            short8 afrag = *(const short8*)(arow + s * 32);
#pragma unroll
            for (int i = 0; i < 4; i++)
                acc[i] = __builtin_amdgcn_mfma_f32_16x16x32_bf16(afrag, bfrag[i][s], acc[i], 0, 0, 0);
        }

        // Epilogue: relu + W2 partials. Lane holds (row=q*4+rg, col) of each tile.
        float sv[4] = {0.f, 0.f, 0.f, 0.f};
#pragma unroll
        for (int i = 0; i < 4; i++) {
            int j = (wave * 4 + i) * 16 + col;
            float uj = u_s[j], wj = w2_s[j];
#pragma unroll
            for (int rg = 0; rg < 4; rg++) {
                float h = acc[i][rg] + uj;
                h = h > 0.f ? h : 0.f;
                sv[rg] += h * wj;
            }
        }
#pragma unroll
        for (int off = 1; off < 16; off <<= 1) {
#pragma unroll
            for (int rg = 0; rg < 4; rg++) sv[rg] += __shfl_xor(sv[rg], off, 64);
        }
        if (col == 0) {
#pragma unroll
            for (int rg = 0; rg < 4; rg++) scoreP[wave][q * 4 + rg] = sv[rg];
        }
        __syncthreads();

        // out[b][d] += sum_m score[m]*item[l0+m][d]; m-range split across halves
        {
            int d = tid & 127;
            int mbase = (tid >> 7) * 8;
#pragma unroll
            for (int mm = 0; mm < 8; mm++) {
                int m = mbase + mm;
                int l = l0 + m;
                float s = scoreP[0][m] + scoreP[1][m] + scoreP[2][m] + scoreP[3][m] + b2;
                s = (l < slen) ? s : 0.f;
                out_val += s * bf2f(Xl[m * XSTRIDE + d]);
            }
        }
    }

    __syncthreads();
    if (tid >= 128) out_s[tid - 128] = out_val;
    __syncthreads();
    if (tid < 128) out[b * 128 + tid] = out_val + out_s[tid];
}

extern "C" void kernel_launch(void* const* d_in, const int* in_sizes, int n_in,
                              void* d_out, int out_size, void* d_ws, size_t ws_size,
                              hipStream_t stream) {
    const float* target   = (const float*)d_in[0];
    const float* item_seq = (const float*)d_in[1];
    const int*   seq_len  = (const int*)d_in[2];
    const float* W1       = (const float*)d_in[3];
    const float* b1       = (const float*)d_in[4];
    const float* W2       = (const float*)d_in[5];
    const float* b2       = (const float*)d_in[6];
    float* out = (float*)d_out;

    char* ws = (char*)d_ws;
    float* Wu    = (float*)ws;                  // 128*256*4 = 131072 B
    short* Wfrag = (short*)(ws + 131072);       // 65536*2   = 131072 B

    make_wu<<<128, 256, 0, stream>>>(W1, Wu);
    repack_w<<<256, 256, 0, stream>>>(W1, Wfrag);
    din_main<<<2048, 256, 0, stream>>>(target, item_seq, seq_len, W2, b2, Wfrag, Wu, b1, out);
}